// Round 1
// baseline (422.223 us; speedup 1.0000x reference)
//
#include <hip/hip_runtime.h>
#include <cstdint>
#include <cmath>

// ---------------- constants ----------------
#define BATCH   65536
#define NREAL   246      // true hidden width
#define NPAD    256      // padded hidden width (multiple of 128)
#define K1REAL  784      // layer-1 K
#define K1PAD   832      // 13*64
#define BINS    100
#define ALPHA   0.1f

typedef __bf16 bf16x8 __attribute__((ext_vector_type(8)));
typedef float  f32x4  __attribute__((ext_vector_type(4)));

__device__ __forceinline__ void gload16(const void* g, void* l) {
    __builtin_amdgcn_global_load_lds(
        (const __attribute__((address_space(1))) void*)g,
        (__attribute__((address_space(3))) void*)l,
        16, 0, 0);
}

// ---------------- weight pad/convert: fp32 -> bf16, zero-padded ----------------
__global__ __launch_bounds__(256)
void pad_weights(const float* __restrict__ W1, const float* __restrict__ W2,
                 const float* __restrict__ W3, const float* __restrict__ W4,
                 const float* __restrict__ W5, const float* __restrict__ W6,
                 __bf16* __restrict__ W1p, __bf16* __restrict__ Wp)
{
    int tid = blockIdx.x * 256 + threadIdx.x;
    const int n1 = NPAD * K1PAD;            // 212992
    if (tid < n1) {
        int row = tid / K1PAD;
        int k   = tid - row * K1PAD;
        float v = (row < NREAL && k < K1REAL) ? W1[row * K1REAL + k] : 0.0f;
        W1p[tid] = (__bf16)v;
    } else {
        int t = tid - n1;
        if (t >= 5 * NPAD * NPAD) return;
        int wsel = t >> 16;                  // which of W2..W6
        int idx  = t & 65535;
        int row  = idx >> 8;
        int k    = idx & 255;
        const float* W = (wsel == 0) ? W2 : (wsel == 1) ? W3 : (wsel == 2) ? W4
                        : (wsel == 3) ? W5 : W6;
        float v = (row < NREAL && k < NREAL) ? W[row * NREAL + k] : 0.0f;
        Wp[t] = (__bf16)v;
    }
}

// ---------------- fused GEMM + bias + leaky_relu ----------------
// C(M x NPAD) = leaky( A(M x K) * B^T + bias ),   B stored (NPAD x bKpad) bf16, padded with zeros.
// Tile 128x128, BK=64, 4 waves, mfma_f32_16x16x32_bf16, m97-style 2-barrier loop.
template<int KT, bool AF32>
__global__ __launch_bounds__(256)
void gemm_leaky(const void* __restrict__ Ain,
                const __bf16* __restrict__ Bp,
                const float* __restrict__ bias,
                __bf16* __restrict__ Cout,
                int bKpad, int aStride)
{
    __shared__ __bf16 As[128 * 64];
    __shared__ __bf16 Bs[128 * 64];

    const int tid = threadIdx.x;
    const int w = tid >> 6, l = tid & 63;

    // XCD-chunked swizzle: nwg=1024, 8 XCDs; consecutive logical blocks (pair sharing A) same XCD
    const int b = blockIdx.x;
    const int L = (b & 7) * (gridDim.x >> 3) + (b >> 3);
    const int m0 = (L >> 1) * 128;
    const int n0 = (L & 1) * 128;

    const int lr = l >> 3;          // row within 8-row chunk
    const int lk = (l & 7) * 8;     // k-element offset within 64

    f32x4 acc[4][4];
#pragma unroll
    for (int i = 0; i < 4; ++i)
#pragma unroll
        for (int j = 0; j < 4; ++j)
            acc[i][j] = f32x4{0.f, 0.f, 0.f, 0.f};

    const int wr = (w >> 1) * 64;   // wave row offset in tile
    const int wc = (w & 1) * 64;    // wave col offset in tile

    auto stage = [&](int kt) {
        const int k0 = kt * 64;
        // B tile: 16 chunks of 8 rows x 64 k
#pragma unroll
        for (int p = 0; p < 4; ++p) {
            int c = p * 4 + w;
            gload16(Bp + (size_t)(n0 + c * 8 + lr) * bKpad + k0 + lk, Bs + c * 512);
        }
        if constexpr (AF32) {
            const float* X = (const float*)Ain;
#pragma unroll
            for (int p = 0; p < 4; ++p) {
                int c = p * 4 + w;
                int row = m0 + c * 8 + lr;
                int k = k0 + lk;
                const float* gx = X + (size_t)row * aStride + k;
                bf16x8 hv;
                if (k + 8 <= K1REAL) {
                    float4 u0 = *(const float4*)gx;
                    float4 u1 = *(const float4*)(gx + 4);
                    hv[0]=(__bf16)u0.x; hv[1]=(__bf16)u0.y; hv[2]=(__bf16)u0.z; hv[3]=(__bf16)u0.w;
                    hv[4]=(__bf16)u1.x; hv[5]=(__bf16)u1.y; hv[6]=(__bf16)u1.z; hv[7]=(__bf16)u1.w;
                } else {
#pragma unroll
                    for (int j = 0; j < 8; ++j)
                        hv[j] = (k + j < K1REAL) ? (__bf16)gx[j] : (__bf16)0.0f;
                }
                *(bf16x8*)(As + c * 512 + l * 8) = hv;
            }
        } else {
            const __bf16* A = (const __bf16*)Ain;
#pragma unroll
            for (int p = 0; p < 4; ++p) {
                int c = p * 4 + w;
                gload16(A + (size_t)(m0 + c * 8 + lr) * aStride + k0 + lk, As + c * 512);
            }
        }
    };

    stage(0);
    for (int kt = 0; kt < KT; ++kt) {
        __syncthreads();   // drain staging (compiler emits vmcnt(0) before barrier)
#pragma unroll
        for (int kk = 0; kk < 2; ++kk) {
            bf16x8 af[4], bfr[4];
#pragma unroll
            for (int i = 0; i < 4; ++i)
                af[i] = *(const bf16x8*)(As + (wr + i * 16 + (l & 15)) * 64 + kk * 32 + (l >> 4) * 8);
#pragma unroll
            for (int j = 0; j < 4; ++j)
                bfr[j] = *(const bf16x8*)(Bs + (wc + j * 16 + (l & 15)) * 64 + kk * 32 + (l >> 4) * 8);
#pragma unroll
            for (int i = 0; i < 4; ++i)
#pragma unroll
                for (int j = 0; j < 4; ++j)
                    acc[i][j] = __builtin_amdgcn_mfma_f32_16x16x32_bf16(af[i], bfr[j], acc[i][j], 0, 0, 0);
        }
        if (kt + 1 < KT) {
            __syncthreads();   // all reads done before overwrite
            stage(kt + 1);
        }
    }

    // epilogue: bias + leaky_relu, write padded bf16 (zeros in cols >= NREAL)
#pragma unroll
    for (int i = 0; i < 4; ++i) {
#pragma unroll
        for (int j = 0; j < 4; ++j) {
            int col = n0 + wc + j * 16 + (l & 15);
            bool cv = col < NREAL;
            float bv = cv ? bias[col] : 0.0f;
#pragma unroll
            for (int r = 0; r < 4; ++r) {
                int row = m0 + wr + i * 16 + (l >> 4) * 4 + r;
                float c = acc[i][j][r] + bv;
                float v = c > 0.0f ? c : ALPHA * c;
                Cout[(size_t)row * NPAD + col] = cv ? (__bf16)v : (__bf16)0.0f;
            }
        }
    }
}

// ---------------- per-row histogram entropy; deterministic two-stage reduce ----------------
__global__ __launch_bounds__(256)
void entropy_kernel(const __bf16* __restrict__ h, float* __restrict__ partial)
{
    __shared__ int   hist[4][BINS];
    __shared__ float rowent[4];
    const int tid = threadIdx.x, w = tid >> 6, l = tid & 63;
    const size_t row = (size_t)blockIdx.x * 4 + w;

    if (l < 50) { hist[w][l] = 0; hist[w][l + 50] = 0; }
    __syncthreads();

    float v0 = (float)h[row * NPAD + l];
    float v1 = (float)h[row * NPAD + l + 64];
    float v2 = (float)h[row * NPAD + l + 128];
    bool  has3 = (l + 192) < NREAL;
    float v3 = has3 ? (float)h[row * NPAD + l + 192] : 0.0f;

    float mn = fminf(fminf(v0, v1), v2);
    float mx = fmaxf(fmaxf(v0, v1), v2);
    if (has3) { mn = fminf(mn, v3); mx = fmaxf(mx, v3); }
#pragma unroll
    for (int off = 32; off; off >>= 1) {
        mn = fminf(mn, __shfl_xor(mn, off, 64));
        mx = fmaxf(mx, __shfl_xor(mx, off, 64));
    }
    float range = mx - mn;
    float rsafe = (range > 0.0f) ? range : 1.0f;

    auto binof = [&](float v) {
        float hn = (v - mn) / rsafe;
        int idx = (int)floorf(hn * 100.0f);
        idx = idx < 0 ? 0 : (idx > BINS - 1 ? BINS - 1 : idx);
        return idx;
    };
    atomicAdd(&hist[w][binof(v0)], 1);
    atomicAdd(&hist[w][binof(v1)], 1);
    atomicAdd(&hist[w][binof(v2)], 1);
    if (has3) atomicAdd(&hist[w][binof(v3)], 1);
    __syncthreads();

    float e = 0.0f;
    int c0 = hist[w][l];
    if (c0 > 0) { float p = (float)c0 / 246.0f; e -= p * logf(p); }
    if (l < BINS - 64) {
        int c1 = hist[w][l + 64];
        if (c1 > 0) { float p = (float)c1 / 246.0f; e -= p * logf(p); }
    }
#pragma unroll
    for (int off = 32; off; off >>= 1) e += __shfl_xor(e, off, 64);
    if (l == 0) rowent[w] = e;
    __syncthreads();
    if (tid == 0)
        partial[blockIdx.x] = rowent[0] + rowent[1] + rowent[2] + rowent[3];
}

__global__ __launch_bounds__(256)
void reduce_kernel(const float* __restrict__ partial, float* __restrict__ out)
{
    __shared__ float s[256];
    const int layer = blockIdx.x;
    const int tid = threadIdx.x;
    float a = 0.0f;
    for (int i = tid; i < 16384; i += 256) a += partial[layer * 16384 + i];
    s[tid] = a;
    __syncthreads();
    for (int st = 128; st; st >>= 1) {
        if (tid < st) s[tid] += s[tid + st];
        __syncthreads();
    }
    if (tid == 0)
        out[(size_t)BATCH * 10 + layer] = s[0] / (float)BATCH + logf((float)BINS);
}

// ---------------- head: relu(h @ W7^T + b7) -> log_softmax ----------------
__global__ __launch_bounds__(256)
void head_kernel(const __bf16* __restrict__ h, const float* __restrict__ W7,
                 const float* __restrict__ b7, float* __restrict__ out)
{
    __shared__ float Ws[10 * NREAL];
    const int tid = threadIdx.x, w = tid >> 6, l = tid & 63;
    for (int i = tid; i < 10 * NREAL; i += 256) Ws[i] = W7[i];
    __syncthreads();

    const size_t row = (size_t)blockIdx.x * 4 + w;
    float acc[10];
#pragma unroll
    for (int j = 0; j < 10; ++j) acc[j] = 0.0f;
    for (int k = l; k < NREAL; k += 64) {
        float a = (float)h[row * NPAD + k];
#pragma unroll
        for (int j = 0; j < 10; ++j) acc[j] += a * Ws[j * NREAL + k];
    }
#pragma unroll
    for (int j = 0; j < 10; ++j)
#pragma unroll
        for (int off = 32; off; off >>= 1) acc[j] += __shfl_xor(acc[j], off, 64);

    float lg[10], m = -1e30f;
#pragma unroll
    for (int j = 0; j < 10; ++j) { lg[j] = fmaxf(acc[j] + b7[j], 0.0f); m = fmaxf(m, lg[j]); }
    float sum = 0.0f;
#pragma unroll
    for (int j = 0; j < 10; ++j) sum += expf(lg[j] - m);
    float ls = m + logf(sum);
    if (l < 10) {
        float mine = 0.0f;
#pragma unroll
        for (int j = 0; j < 10; ++j) if (l == j) mine = lg[j];
        out[row * 10 + l] = mine - ls;
    }
}

// ---------------- launch ----------------
extern "C" void kernel_launch(void* const* d_in, const int* in_sizes, int n_in,
                              void* d_out, int out_size, void* d_ws, size_t ws_size,
                              hipStream_t stream)
{
    (void)in_sizes; (void)n_in; (void)out_size; (void)ws_size;

    const float* x  = (const float*)d_in[0];
    const float* W1 = (const float*)d_in[1];
    const float* b1 = (const float*)d_in[2];
    const float* W2 = (const float*)d_in[3];
    const float* b2 = (const float*)d_in[4];
    const float* W3 = (const float*)d_in[5];
    const float* b3 = (const float*)d_in[6];
    const float* W4 = (const float*)d_in[7];
    const float* b4 = (const float*)d_in[8];
    const float* W5 = (const float*)d_in[9];
    const float* b5 = (const float*)d_in[10];
    const float* W6 = (const float*)d_in[11];
    const float* b6 = (const float*)d_in[12];
    const float* W7 = (const float*)d_in[13];
    const float* b7 = (const float*)d_in[14];

    char* ws = (char*)d_ws;
    // ws layout (bytes):
    //   0         : hA  (65536*256 bf16 = 32 MiB)
    //   33554432  : hB  (32 MiB)
    //   67108864  : W1p (256*832 bf16)
    //   67534848  : Wp  (5 * 256*256 bf16)
    //   68190208  : partial (6 * 16384 f32)   -> total ~68.6 MB
    __bf16* hA  = (__bf16*)(ws);
    __bf16* hB  = (__bf16*)(ws + 33554432);
    __bf16* W1p = (__bf16*)(ws + 67108864);
    __bf16* Wp  = (__bf16*)(ws + 67534848);
    float*  partial = (float*)(ws + 68190208);
    float*  out = (float*)d_out;

    pad_weights<<<2112, 256, 0, stream>>>(W1, W2, W3, W4, W5, W6, W1p, Wp);

    gemm_leaky<13, true ><<<1024, 256, 0, stream>>>(x,  W1p,            b1, hA, K1PAD, K1REAL);
    entropy_kernel<<<16384, 256, 0, stream>>>(hA, partial + 0 * 16384);
    gemm_leaky<4,  false><<<1024, 256, 0, stream>>>(hA, Wp + 0 * 65536, b2, hB, NPAD, NPAD);
    entropy_kernel<<<16384, 256, 0, stream>>>(hB, partial + 1 * 16384);
    gemm_leaky<4,  false><<<1024, 256, 0, stream>>>(hB, Wp + 1 * 65536, b3, hA, NPAD, NPAD);
    entropy_kernel<<<16384, 256, 0, stream>>>(hA, partial + 2 * 16384);
    gemm_leaky<4,  false><<<1024, 256, 0, stream>>>(hA, Wp + 2 * 65536, b4, hB, NPAD, NPAD);
    entropy_kernel<<<16384, 256, 0, stream>>>(hB, partial + 3 * 16384);
    gemm_leaky<4,  false><<<1024, 256, 0, stream>>>(hB, Wp + 3 * 65536, b5, hA, NPAD, NPAD);
    entropy_kernel<<<16384, 256, 0, stream>>>(hA, partial + 4 * 16384);
    gemm_leaky<4,  false><<<1024, 256, 0, stream>>>(hA, Wp + 4 * 65536, b6, hB, NPAD, NPAD);
    entropy_kernel<<<16384, 256, 0, stream>>>(hB, partial + 5 * 16384);

    head_kernel<<<16384, 256, 0, stream>>>(hB, W7, b7, out);
    reduce_kernel<<<6, 256, 0, stream>>>(partial, out);
}

// Round 2
// 354.455 us; speedup vs baseline: 1.1912x; 1.1912x over previous
//
#include <hip/hip_runtime.h>
#include <cstdint>
#include <cmath>

#define BATCH 65536
#define NREAL 246
#define NPAD  256
#define K1    784
#define K1PAD 832
#define BINS  100
#define ALPHA 0.1f
#define RB    128            // rows per block
#define NBLK  (BATCH/RB)     // 512

typedef __bf16 bf16x8 __attribute__((ext_vector_type(8)));
typedef __bf16 bf16x4 __attribute__((ext_vector_type(4)));
typedef float  f32x4  __attribute__((ext_vector_type(4)));

// ---------------- weight pad/convert: fp32 -> bf16, zero-padded ----------------
__global__ __launch_bounds__(256)
void pad_weights(const float* __restrict__ W1, const float* __restrict__ W2,
                 const float* __restrict__ W3, const float* __restrict__ W4,
                 const float* __restrict__ W5, const float* __restrict__ W6,
                 const float* __restrict__ W7,
                 __bf16* __restrict__ W1p, __bf16* __restrict__ Wp,
                 __bf16* __restrict__ W7p)
{
    int tid = blockIdx.x * 256 + threadIdx.x;
    const int n1 = NPAD * K1PAD;        // 212992
    const int n2 = 5 * NPAD * NPAD;     // 327680
    if (tid < n1) {
        int row = tid / K1PAD;
        int k   = tid - row * K1PAD;
        W1p[tid] = (__bf16)((row < NREAL && k < K1) ? W1[row * K1 + k] : 0.0f);
    } else if (tid < n1 + n2) {
        int t = tid - n1;
        int wsel = t >> 16;
        int idx  = t & 65535;
        int row  = idx >> 8, k = idx & 255;
        const float* W = (wsel == 0) ? W2 : (wsel == 1) ? W3 : (wsel == 2) ? W4
                        : (wsel == 3) ? W5 : W6;
        Wp[t] = (__bf16)((row < NREAL && k < NREAL) ? W[row * NREAL + k] : 0.0f);
    } else if (tid < n1 + n2 + 16 * NPAD) {
        int t = tid - n1 - n2;
        int row = t >> 8, k = t & 255;
        W7p[t] = (__bf16)((row < 10 && k < NREAL) ? W7[row * NREAL + k] : 0.0f);
    }
}

// ---------------- megakernel: all 7 layers + 6 entropies + log_softmax ----------------
__global__ __launch_bounds__(512)
void mega(const float* __restrict__ x,
          const __bf16* __restrict__ W1p,
          const __bf16* __restrict__ Wp,
          const __bf16* __restrict__ W7p,
          const float* __restrict__ b1, const float* __restrict__ b2,
          const float* __restrict__ b3, const float* __restrict__ b4,
          const float* __restrict__ b5, const float* __restrict__ b6,
          const float* __restrict__ b7,
          float* __restrict__ out, float* __restrict__ partial)
{
    __shared__ __bf16 Hs[RB * NPAD];     // 64 KiB activation tile, XOR-swizzled
    __shared__ char   aux[32768];        // L1 A-staging dbuf; later hist/went/lut
    char* Hb = (char*)Hs;

    const int tid = threadIdx.x;
    const int w = tid >> 6, l = tid & 63;
    const int lane16 = l & 15, lane4 = l >> 4;
    const int wr = (w >> 2) * 64;        // wave row base (2 wave-rows)
    const int wc = (w & 3) * 64;         // wave col base (4 wave-cols)
    const int m0 = blockIdx.x * RB;
    const int swzA = (lane16 & 7) << 4;  // A-frag read swizzle

    f32x4 acc[4][4];
#pragma unroll
    for (int i = 0; i < 4; ++i)
#pragma unroll
        for (int j = 0; j < 4; ++j) acc[i][j] = f32x4{0.f, 0.f, 0.f, 0.f};

    // ---- B fragments: direct global->reg (weights are L2-resident) ----
    auto loadB = [&](bf16x8 (&dst)[2][4], const __bf16* Bbase, int Kb, int kt) {
#pragma unroll
        for (int kk = 0; kk < 2; ++kk)
#pragma unroll
            for (int j = 0; j < 4; ++j) {
                int col = wc + j * 16 + lane16;
                dst[kk][j] = *(const bf16x8*)(Bbase + (size_t)col * Kb + kt * 64 + kk * 32 + lane4 * 8);
            }
    };

    // ---- L1 x staging: global fp32 -> bf16 -> swizzled LDS ----
    const int srow = tid >> 2, skq = tid & 3;
    auto stageIssue = [&](int kt, float4 (&xs)[4]) {
        int k0 = kt * 64 + skq * 16;
        if (k0 + 16 <= K1) {
            const float* gx = x + (size_t)(m0 + srow) * K1 + k0;
#pragma unroll
            for (int q = 0; q < 4; ++q) xs[q] = *(const float4*)(gx + q * 4);
        } else {
#pragma unroll
            for (int q = 0; q < 4; ++q) xs[q] = float4{0.f, 0.f, 0.f, 0.f};
        }
    };
    auto stageWrite = [&](int pdst, const float4 (&xs)[4]) {
        char* Ab = aux + pdst * 16384;
        bf16x8 h0, h1;
        h0[0]=(__bf16)xs[0].x; h0[1]=(__bf16)xs[0].y; h0[2]=(__bf16)xs[0].z; h0[3]=(__bf16)xs[0].w;
        h0[4]=(__bf16)xs[1].x; h0[5]=(__bf16)xs[1].y; h0[6]=(__bf16)xs[1].z; h0[7]=(__bf16)xs[1].w;
        h1[0]=(__bf16)xs[2].x; h1[1]=(__bf16)xs[2].y; h1[2]=(__bf16)xs[2].z; h1[3]=(__bf16)xs[2].w;
        h1[4]=(__bf16)xs[3].x; h1[5]=(__bf16)xs[3].y; h1[6]=(__bf16)xs[3].z; h1[7]=(__bf16)xs[3].w;
        int s = (srow & 7) << 4;
        int base = srow * 128;
        *(bf16x8*)(Ab + base + ((skq * 32)      ^ s)) = h0;
        *(bf16x8*)(Ab + base + ((skq * 32 + 16) ^ s)) = h1;
    };

    auto computeL1 = [&](const bf16x8 (&bfr)[2][4], int pcur) {
        const char* Ab = aux + pcur * 16384;
#pragma unroll
        for (int kk = 0; kk < 2; ++kk) {
            bf16x8 af[4];
#pragma unroll
            for (int i = 0; i < 4; ++i) {
                int row = wr + i * 16 + lane16;
                int kb = kk * 64 + lane4 * 16;
                af[i] = *(const bf16x8*)(Ab + row * 128 + (kb ^ swzA));
            }
#pragma unroll
            for (int i = 0; i < 4; ++i)
#pragma unroll
                for (int j = 0; j < 4; ++j)
                    acc[i][j] = __builtin_amdgcn_mfma_f32_16x16x32_bf16(af[i], bfr[kk][j], acc[i][j], 0, 0, 0);
        }
    };

    auto computeMid = [&](const bf16x8 (&bfr)[2][4], int kt) {
#pragma unroll
        for (int kk = 0; kk < 2; ++kk) {
            bf16x8 af[4];
#pragma unroll
            for (int i = 0; i < 4; ++i) {
                int row = wr + i * 16 + lane16;
                int kb = kt * 128 + kk * 64 + lane4 * 16;
                af[i] = *(const bf16x8*)(Hb + row * 512 + (kb ^ swzA));
            }
#pragma unroll
            for (int i = 0; i < 4; ++i)
#pragma unroll
                for (int j = 0; j < 4; ++j)
                    acc[i][j] = __builtin_amdgcn_mfma_f32_16x16x32_bf16(af[i], bfr[kk][j], acc[i][j], 0, 0, 0);
        }
    };

    // bias + leaky_relu, write swizzled bf16 into Hs (zeros for cols >= 246)
    auto epilogue = [&](const float* bias) {
#pragma unroll
        for (int j = 0; j < 4; ++j) {
            int col = wc + j * 16 + lane16;
            bool cv = col < NREAL;
            float bv = cv ? bias[col] : 0.0f;
#pragma unroll
            for (int i = 0; i < 4; ++i) {
#pragma unroll
                for (int r = 0; r < 4; ++r) {
                    int row = wr + i * 16 + lane4 * 4 + r;
                    float v = acc[i][j][r] + bv;
                    v = v > 0.0f ? v : ALPHA * v;
                    *(__bf16*)(Hb + row * 512 + ((col * 2) ^ ((row & 7) << 4))) =
                        cv ? (__bf16)v : (__bf16)0.0f;
                }
            }
        }
    };

    const float LN246 = logf(246.0f);

    // per-layer entropy, fully in-LDS; deterministic (integer histogram + fixed-order sums)
    auto entropy = [&](int li) {
        int*   hist = (int*)aux + w * 100;
        float* went = (float*)(aux + 3200);
        float* lut  = (float*)(aux + 3264);
        float wsum = 0.0f;
        for (int it = 0; it < 16; ++it) {
            int row = w * 16 + it;
            if (l < 50) { hist[l] = 0; hist[l + 50] = 0; }
            asm volatile("s_waitcnt lgkmcnt(0)" ::: "memory");
            int kb = (l * 8) ^ ((it & 7) << 4);
            bf16x4 hv = *(const bf16x4*)(Hb + row * 512 + kb);
            float v[4];
#pragma unroll
            for (int e = 0; e < 4; ++e) v[e] = (float)hv[e];
            int c0 = l * 4;
            float mn = 1e30f, mx = -1e30f;
#pragma unroll
            for (int e = 0; e < 4; ++e)
                if (c0 + e < NREAL) { mn = fminf(mn, v[e]); mx = fmaxf(mx, v[e]); }
#pragma unroll
            for (int off = 32; off; off >>= 1) {
                mn = fminf(mn, __shfl_xor(mn, off, 64));
                mx = fmaxf(mx, __shfl_xor(mx, off, 64));
            }
            float range = mx - mn;
            float rr = (range > 0.0f) ? 1.0f / range : 0.0f;
#pragma unroll
            for (int e = 0; e < 4; ++e) {
                if (c0 + e < NREAL) {
                    int idx = (int)floorf((v[e] - mn) * rr * 100.0f);
                    idx = idx < 0 ? 0 : (idx > BINS - 1 ? BINS - 1 : idx);
                    atomicAdd(&hist[idx], 1);
                }
            }
            asm volatile("s_waitcnt lgkmcnt(0)" ::: "memory");
            float S = lut[hist[l]];
            if (l < BINS - 64) S += lut[hist[64 + l]];
#pragma unroll
            for (int off = 32; off; off >>= 1) S += __shfl_xor(S, off, 64);
            wsum += LN246 - S * (1.0f / 246.0f);
        }
        if (l == 0) went[w] = wsum;
        __syncthreads();
        if (tid == 0) {
            float s = 0.0f;
#pragma unroll
            for (int q = 0; q < 8; ++q) s += went[q];
            partial[li * NBLK + blockIdx.x] = s;
        }
    };

    // ================= layer 1 (K=784, x streamed from HBM) =================
    {
        bf16x8 bA[2][4], bB[2][4];
        loadB(bA, W1p, K1PAD, 0);
        { float4 xs[4]; stageIssue(0, xs); stageWrite(0, xs); }
        for (int n = 0; n < 6; ++n) {
            int kt = 2 * n;
            __syncthreads();
            { float4 xn[4];
              stageIssue(kt + 1, xn); loadB(bB, W1p, K1PAD, kt + 1);
              computeL1(bA, 0);
              stageWrite(1, xn); }
            __syncthreads();
            { float4 xn[4];
              stageIssue(kt + 2, xn); loadB(bA, W1p, K1PAD, kt + 2);
              computeL1(bB, 1);
              stageWrite(0, xn); }
        }
        __syncthreads();
        computeL1(bA, 0);   // kt = 12 (remainder, zero-padded)
    }
    __syncthreads();
    {   // c*ln(c) LUT (aux staging region is free now)
        float* lut = (float*)(aux + 3264);
        for (int c = tid; c < 247; c += 512) lut[c] = (c > 0) ? (float)c * logf((float)c) : 0.0f;
    }
    epilogue(b1);
    __syncthreads();
    entropy(0);

    // ================= layers 2..6 (A in LDS, B direct from L2) =================
    const float* bsel[5] = {b2, b3, b4, b5, b6};
    for (int li = 0; li < 5; ++li) {
        const __bf16* Bp = Wp + (size_t)li * (NPAD * NPAD);
#pragma unroll
        for (int i = 0; i < 4; ++i)
#pragma unroll
            for (int j = 0; j < 4; ++j) acc[i][j] = f32x4{0.f, 0.f, 0.f, 0.f};

        bf16x8 mA[2][4], mB[2][4];
        loadB(mA, Bp, NPAD, 0);
        loadB(mB, Bp, NPAD, 1);  computeMid(mA, 0);
        loadB(mA, Bp, NPAD, 2);  computeMid(mB, 1);
        loadB(mB, Bp, NPAD, 3);  computeMid(mA, 2);
                                 computeMid(mB, 3);
        __syncthreads();
        epilogue(bsel[li]);
        __syncthreads();
        entropy(li + 1);
    }

    // ================= head: one 16x16 MFMA per wave + log_softmax =================
    {
        f32x4 hacc = f32x4{0.f, 0.f, 0.f, 0.f};
#pragma unroll
        for (int kt = 0; kt < 8; ++kt) {
            int row = w * 16 + lane16;
            int kb = kt * 64 + lane4 * 16;
            bf16x8 af = *(const bf16x8*)(Hb + row * 512 + (kb ^ swzA));
            bf16x8 bf = *(const bf16x8*)(W7p + (size_t)lane16 * NPAD + kt * 32 + lane4 * 8);
            hacc = __builtin_amdgcn_mfma_f32_16x16x32_bf16(af, bf, hacc, 0, 0, 0);
        }
        float bv = (lane16 < 10) ? b7[lane16] : 0.0f;
#pragma unroll
        for (int r = 0; r < 4; ++r) {
            float lg = fmaxf(hacc[r] + bv, 0.0f);
            float vm = (lane16 < 10) ? lg : -1e30f;
#pragma unroll
            for (int off = 8; off; off >>= 1) vm = fmaxf(vm, __shfl_xor(vm, off, 64));
            float ex = (lane16 < 10) ? expf(lg - vm) : 0.0f;
#pragma unroll
            for (int off = 8; off; off >>= 1) ex += __shfl_xor(ex, off, 64);
            float ls = vm + logf(ex);
            if (lane16 < 10) {
                int grow = m0 + w * 16 + lane4 * 4 + r;
                out[(size_t)grow * 10 + lane16] = lg - ls;
            }
        }
    }
}

// ---------------- final entropy mean (deterministic fixed-order) ----------------
__global__ __launch_bounds__(256)
void reduce_kernel(const float* __restrict__ partial, float* __restrict__ out)
{
    __shared__ float s[256];
    const int li = blockIdx.x, tid = threadIdx.x;
    float a = partial[li * NBLK + tid] + partial[li * NBLK + 256 + tid];
    s[tid] = a;
    __syncthreads();
    for (int st = 128; st; st >>= 1) {
        if (tid < st) s[tid] += s[tid + st];
        __syncthreads();
    }
    if (tid == 0)
        out[(size_t)BATCH * 10 + li] = s[0] / (float)BATCH + logf((float)BINS);
}

// ---------------- launch ----------------
extern "C" void kernel_launch(void* const* d_in, const int* in_sizes, int n_in,
                              void* d_out, int out_size, void* d_ws, size_t ws_size,
                              hipStream_t stream)
{
    (void)in_sizes; (void)n_in; (void)out_size; (void)ws_size;

    const float* x  = (const float*)d_in[0];
    const float* W1 = (const float*)d_in[1];
    const float* b1 = (const float*)d_in[2];
    const float* W2 = (const float*)d_in[3];
    const float* b2 = (const float*)d_in[4];
    const float* W3 = (const float*)d_in[5];
    const float* b3 = (const float*)d_in[6];
    const float* W4 = (const float*)d_in[7];
    const float* b4 = (const float*)d_in[8];
    const float* W5 = (const float*)d_in[9];
    const float* b5 = (const float*)d_in[10];
    const float* W6 = (const float*)d_in[11];
    const float* b6 = (const float*)d_in[12];
    const float* W7 = (const float*)d_in[13];
    const float* b7 = (const float*)d_in[14];

    char* ws = (char*)d_ws;
    // ws layout (bytes):
    //   0       : W1p  256*832 bf16  = 425984
    //   425984  : Wp   5*256*256 bf16 = 655360
    //   1081344 : W7p  16*256 bf16   = 8192
    //   1089536 : partial 6*512 f32  = 12288
    __bf16* W1p = (__bf16*)(ws);
    __bf16* Wp  = (__bf16*)(ws + 425984);
    __bf16* W7p = (__bf16*)(ws + 1081344);
    float*  partial = (float*)(ws + 1089536);
    float*  out = (float*)d_out;

    pad_weights<<<2128, 256, 0, stream>>>(W1, W2, W3, W4, W5, W6, W7, W1p, Wp, W7p);
    mega<<<NBLK, 512, 0, stream>>>(x, W1p, Wp, W7p, b1, b2, b3, b4, b5, b6, b7, out, partial);
    reduce_kernel<<<6, 256, 0, stream>>>(partial, out);
}